// Round 9
// baseline (219.600 us; speedup 1.0000x reference)
//
#include <hip/hip_runtime.h>
#include <hip/hip_cooperative_groups.h>

namespace cg = cooperative_groups;

#define NN 16384
#define NCB 8
#define DIM 32
#define CB 1024
#define RPB 512         // (n,k) pairs scanned per block (one k)
#define QC 256          // codebook entries per wave (quarter)
#define TILE 64         // entries per LDS tile
#define NTL (QC / TILE) // 4 tiles per wave

// Kernel A: csqb[k*CB+c] = ||codebook[k,c]||^2 + rate_bias[k,c]
__global__ __launch_bounds__(256) void vq_csq(const float* __restrict__ cb,
                                              const float* __restrict__ rb,
                                              float* __restrict__ out) {
    int i = blockIdx.x * 256 + threadIdx.x;
    if (i >= NCB * CB) return;
    const float4* c4 = reinterpret_cast<const float4*>(cb + (size_t)i * DIM);
    float s0 = 0.f, s1 = 0.f, s2 = 0.f, s3 = 0.f;
#pragma unroll
    for (int j = 0; j < 8; ++j) {
        float4 v = c4[j];
        s0 = fmaf(v.x, v.x, s0);
        s1 = fmaf(v.y, v.y, s1);
        s2 = fmaf(v.z, v.z, s2);
        s3 = fmaf(v.w, v.w, s3);
    }
    out[i] = ((s0 + s1) + (s2 + s3)) + rb[i];
}

// Cooperative fused kernel: 256 blocks (1/CU) x 512 threads (8 waves).
// Phase A: R8's scan machinery (wave (rh,q) scans quarter q for row-half rh,
//   4 rows/thread from per-wave dbuf LDS tiles) BUT the interleaved one_hot
//   zero-fill now targets the block's LINEAR 2MB slice [bid*2MB,+2MB)
//   (sequential 1KB/wave stores -> fillBuffer-rate drain), decoupled from the
//   scanned rows. Scan results: idx + x_hat written directly; argmin index
//   bi published to d_ws with agent-scope stores.
// grid.sync(): all zeros + bi stores complete/visible.
// Phase B: block bid = slice owner writes the 512 "1.0"s that land in its
//   own slice (pairs p in [bid*512,+512)), reading bi agent-scope. Every
//   one_hot byte has ONE writer; zero->1.0 order is same-block, same-L2.
__global__ __launch_bounds__(512, 2) void vq_fused(
    const float* __restrict__ x, const float* __restrict__ cb,
    const float* __restrict__ csqb, float* __restrict__ xhat,
    float* __restrict__ onehot, float* __restrict__ idxf,
    int* __restrict__ bi_ws) {
    __shared__ float4 tiles[8][2][TILE * 8];  // 128 KB
    __shared__ float pd[4][RPB];              // 8 KB
    __shared__ int pi[4][RPB];                // 8 KB -> 144 KB: 1 block/CU

    const int tid = threadIdx.x;
    const int w = tid >> 6;
    const int lane = tid & 63;
    const int rh = w >> 2;  // row half
    const int q = w & 3;    // codebook quarter
    const int bid = blockIdx.x;
    const int k = bid & (NCB - 1);
    const int n0 = (bid >> 3) * RPB;

    const float4* cbk4 =
        reinterpret_cast<const float4*>(cb + (size_t)k * CB * DIM);
    const float* cqk = csqb + (size_t)k * CB;

    // ---- 4 x-rows -> registers; ||x||^2 (frozen chain) ----
    const int rbase = rh * 256 + lane * 4;
    float4 xr[4][8];
    float xsq[4];
#pragma unroll
    for (int j = 0; j < 4; ++j) {
        const int n = n0 + rbase + j;
        const float4* xp =
            reinterpret_cast<const float4*>(x + ((size_t)n * NCB + k) * DIM);
#pragma unroll
        for (int jj = 0; jj < 8; ++jj) xr[j][jj] = xp[jj];
        float q0 = 0.f, q1 = 0.f, q2 = 0.f, q3 = 0.f;
#pragma unroll
        for (int jj = 0; jj < 8; ++jj) {
            q0 = fmaf(xr[j][jj].x, xr[j][jj].x, q0);
            q1 = fmaf(xr[j][jj].y, xr[j][jj].y, q1);
            q2 = fmaf(xr[j][jj].z, xr[j][jj].z, q2);
            q3 = fmaf(xr[j][jj].w, xr[j][jj].w, q3);
        }
        xsq[j] = (q0 + q1) + (q2 + q3);
    }

    float best[4];
    int bi[4];
#pragma unroll
    for (int j = 0; j < 4; ++j) {
        best[j] = 3.4028235e38f;
        bi[j] = 0;
    }

    // ---- prologue: stage tile 0 of this wave's quarter ----
    const int qbase = q * QC;
    float4 st[8];
    float cq_cur, cq_nxt = 0.f;
#pragma unroll
    for (int i = 0; i < 8; ++i) st[i] = cbk4[(size_t)qbase * 8 + i * 64 + lane];
    cq_cur = cqk[qbase + lane];
#pragma unroll
    for (int i = 0; i < 8; ++i) tiles[w][0][i * 64 + lane] = st[i];

    // linear zero-fill slice: wave w owns float4s [bid*131072 + w*16384, +16384)
    float4* zbase = reinterpret_cast<float4*>(onehot) + (size_t)bid * 131072 +
                    (size_t)w * 16384;
    const float4 z4 = make_float4(0.f, 0.f, 0.f, 0.f);

    for (int t = 0; t < NTL; ++t) {
        const int b = t & 1;
        // prefetch next tile into regs (loads are oldest in the vmcnt FIFO)
        if (t < NTL - 1) {
#pragma unroll
            for (int i = 0; i < 8; ++i)
                st[i] = cbk4[((size_t)qbase + (t + 1) * TILE) * 8 + i * 64 +
                             lane];
            cq_nxt = cqk[qbase + (t + 1) * TILE + lane];
        }

        const float4* buf = &tiles[w][b][0];
#pragma unroll 2
        for (int c = 0; c < TILE; ++c) {
            // interleaved LINEAR zero-fill: 1 KB per c, sequential addresses
            zbase[(size_t)(t * TILE + c) * 64 + lane] = z4;

            const float cqv = __int_as_float(
                __builtin_amdgcn_readlane(__float_as_int(cq_cur), c));
            float4 A[8];
#pragma unroll
            for (int jj = 0; jj < 8; ++jj) A[jj] = buf[c * 8 + jj];
            const int cg = qbase + t * TILE + c;

#pragma unroll
            for (int j = 0; j < 4; ++j) {
                // frozen round-2 chain order
                float d0 = 0.f, d1 = 0.f, d2 = 0.f, d3 = 0.f;
#pragma unroll
                for (int jj = 0; jj < 8; ++jj) {
                    d0 = fmaf(xr[j][jj].x, A[jj].x, d0);
                    d1 = fmaf(xr[j][jj].y, A[jj].y, d1);
                    d2 = fmaf(xr[j][jj].z, A[jj].z, d2);
                    d3 = fmaf(xr[j][jj].w, A[jj].w, d3);
                }
                const float dot = (d0 + d1) + (d2 + d3);
                const float dist = fmaf(-2.f, dot, xsq[j] + cqv);
                if (dist < best[j]) {  // strict <: first occurrence in quarter
                    best[j] = dist;
                    bi[j] = cg;
                }
            }
        }

        if (t < NTL - 1) {
#pragma unroll
            for (int i = 0; i < 8; ++i) tiles[w][b ^ 1][i * 64 + lane] = st[i];
            cq_cur = cq_nxt;
        }
    }

    // ---- publish per-quarter partials ----
#pragma unroll
    for (int j = 0; j < 4; ++j) {
        pd[q][rbase + j] = best[j];
        pi[q][rbase + j] = bi[j];
    }
    __syncthreads();

    // ---- combine quarters; write idx + x_hat; publish bi (agent scope) ----
    {
        const int r = tid;
        float bd = pd[0][r];
        int bx = pi[0][r];
#pragma unroll
        for (int qq = 1; qq < 4; ++qq) {
            const float dq = pd[qq][r];
            const int iq = pi[qq][r];
            // ascending quarters => on tie keep lower (earlier) index
            if (dq < bd) {
                bd = dq;
                bx = iq;
            }
        }
        const int n = n0 + r;
        idxf[(size_t)n * NCB + k] = (float)bx;
        const float4* src = cbk4 + (size_t)bx * 8;
        float4* dst =
            reinterpret_cast<float4*>(xhat + ((size_t)n * NCB + k) * DIM);
#pragma unroll
        for (int jj = 0; jj < 8; ++jj) dst[jj] = src[jj];
        __hip_atomic_store(&bi_ws[(size_t)n * NCB + k], bx, __ATOMIC_RELAXED,
                           __HIP_MEMORY_SCOPE_AGENT);
    }

    // ---- all blocks' zeros + bi visible ----
    cg::this_grid().sync();

    // ---- Phase B: slice owner writes its slice's 1.0s ----
    {
        const int p = bid * 512 + tid;  // flattened pair n*8+k in slice bid
        const int bv = __hip_atomic_load(&bi_ws[p], __ATOMIC_RELAXED,
                                         __HIP_MEMORY_SCOPE_AGENT);
        onehot[(size_t)p * CB + bv] = 1.0f;
    }
}

extern "C" void kernel_launch(void* const* d_in, const int* in_sizes, int n_in,
                              void* d_out, int out_size, void* d_ws,
                              size_t ws_size, hipStream_t stream) {
    const float* x = (const float*)d_in[0];
    const float* cb = (const float*)d_in[1];
    const float* rb = (const float*)d_in[2];

    float* out = (float*)d_out;
    float* xhat = out;                             // N*NCB*DIM
    float* onehot = out + (size_t)NN * NCB * DIM;  // N*NCB*CB
    float* idxf = onehot + (size_t)NN * NCB * CB;  // N*NCB

    float* csqb = (float*)d_ws;                    // 32 KB
    int* bi_ws = (int*)((char*)d_ws + 65536);      // 512 KB pair->index

    vq_csq<<<(NCB * CB + 255) / 256, 256, 0, stream>>>(cb, rb, csqb);

    void* args[] = {(void*)&x,      (void*)&cb,   (void*)&csqb,
                    (void*)&xhat,   (void*)&onehot, (void*)&idxf,
                    (void*)&bi_ws};
    hipLaunchCooperativeKernel((void*)vq_fused, dim3((NN / RPB) * NCB),
                               dim3(512), args, 0, stream);
}

// Round 10
// 175.427 us; speedup vs baseline: 1.2518x; 1.2518x over previous
//
#include <hip/hip_runtime.h>

typedef float f32x2 __attribute__((ext_vector_type(2)));
typedef float f32x4 __attribute__((ext_vector_type(4)));

#define NN 16384
#define NCB 8
#define DIM 32
#define CB 1024
#define RPB 512         // rows per block (one k)
#define QC 256          // codebook entries per wave (quarter)
#define TILE 32         // entries per LDS tile
#define NTL (QC / TILE) // 8 tiles per wave

__device__ __forceinline__ void gload_lds16(const void* g, void* l) {
    __builtin_amdgcn_global_load_lds(
        (const __attribute__((address_space(1))) unsigned int*)g,
        (__attribute__((address_space(3))) unsigned int*)l, 16, 0, 0);
}

// packed 2xFP32 FMA; each half is bit-identical to scalar fmaf -> frozen
// numerics preserved (d.lo = fma(a.lo,b.lo,c.lo), d.hi likewise).
__device__ __forceinline__ f32x2 pkfma(f32x2 a, f32x2 b, f32x2 c) {
    f32x2 d = c;
    asm("v_pk_fma_f32 %0, %1, %2, %0" : "+v"(d) : "v"(a), "v"(b));
    return d;
}

// Kernel A: csqb[k*CB+c] = ||codebook[k,c]||^2 + rate_bias[k,c]
__global__ __launch_bounds__(256) void vq_csq(const float* __restrict__ cb,
                                              const float* __restrict__ rb,
                                              float* __restrict__ out) {
    int i = blockIdx.x * 256 + threadIdx.x;
    if (i >= NCB * CB) return;
    const float4* c4 = reinterpret_cast<const float4*>(cb + (size_t)i * DIM);
    float s0 = 0.f, s1 = 0.f, s2 = 0.f, s3 = 0.f;
#pragma unroll
    for (int j = 0; j < 8; ++j) {
        float4 v = c4[j];
        s0 = fmaf(v.x, v.x, s0);
        s1 = fmaf(v.y, v.y, s1);
        s2 = fmaf(v.z, v.z, s2);
        s3 = fmaf(v.w, v.w, s3);
    }
    out[i] = ((s0 + s1) + (s2 + s3)) + rb[i];
}

// Fused kernel: 256 blocks x 512 threads (8 waves). Wave (rh,q) scans
// codebook quarter q for row-half rh, 4 rows/thread. Tiles staged with
// global_load_lds (async, no VGPR round-trip); per-iter VMEM FIFO is exactly
// [32 zero-stores][4 gloads], so the counted s_waitcnt vmcnt(36) completes
// the tile WITHOUT draining stores. pk_fma halves VALU. cq preloaded into 4
// regs (statically indexed). One __syncthreads orders zeros before 1.0s.
__global__ __launch_bounds__(512, 1) void vq_fused(
    const float* __restrict__ x, const float* __restrict__ cb,
    const float* __restrict__ csqb, float* __restrict__ xhat,
    float* __restrict__ onehot, float* __restrict__ idxf) {
    __shared__ f32x4 tiles[8][2][TILE * 8];  // 8 waves x dbuf x 4 KB = 64 KB
    __shared__ float pd[4][RPB];             // 8 KB
    __shared__ int pi[4][RPB];               // 8 KB  -> 80 KB total

    const int tid = threadIdx.x;
    const int w = tid >> 6;
    const int lane = tid & 63;
    const int rh = w >> 2;  // row half
    const int q = w & 3;    // codebook quarter
    const int k = blockIdx.x & (NCB - 1);
    const int n0 = (blockIdx.x >> 3) * RPB;

    const f32x4* cbk4 =
        reinterpret_cast<const f32x4*>(cb + (size_t)k * CB * DIM);
    const float* cqk = csqb + (size_t)k * CB;

    // ---- 4 x-rows -> registers as f32x2 pairs; ||x||^2 (frozen chain) ----
    const int rbase = rh * 256 + lane * 4;
    f32x2 xlo[4][8], xhi[4][8];
    float xsq[4];
#pragma unroll
    for (int j = 0; j < 4; ++j) {
        const int n = n0 + rbase + j;
        const f32x4* xp =
            reinterpret_cast<const f32x4*>(x + ((size_t)n * NCB + k) * DIM);
        f32x4 xt[8];
#pragma unroll
        for (int jj = 0; jj < 8; ++jj) xt[jj] = xp[jj];
        float q0 = 0.f, q1 = 0.f, q2 = 0.f, q3 = 0.f;
#pragma unroll
        for (int jj = 0; jj < 8; ++jj) {
            q0 = fmaf(xt[jj].x, xt[jj].x, q0);
            q1 = fmaf(xt[jj].y, xt[jj].y, q1);
            q2 = fmaf(xt[jj].z, xt[jj].z, q2);
            q3 = fmaf(xt[jj].w, xt[jj].w, q3);
        }
        xsq[j] = (q0 + q1) + (q2 + q3);
#pragma unroll
        for (int jj = 0; jj < 8; ++jj) {
            xlo[j][jj] = __builtin_shufflevector(xt[jj], xt[jj], 0, 1);
            xhi[j][jj] = __builtin_shufflevector(xt[jj], xt[jj], 2, 3);
        }
    }

    float best[4];
    int bi[4];
#pragma unroll
    for (int j = 0; j < 4; ++j) {
        best[j] = 3.4028235e38f;
        bi[j] = 0;
    }

    const int qbase = q * QC;
    // preload the whole quarter's cq into 4 regs (64 lanes x 4)
    float cqall[4];
#pragma unroll
    for (int i = 0; i < 4; ++i) cqall[i] = cqk[qbase + i * 64 + lane];

    // prologue: stage tile 0
    __builtin_amdgcn_sched_barrier(0);
#pragma unroll
    for (int i = 0; i < 4; ++i)
        gload_lds16(cbk4 + (size_t)qbase * 8 + i * 64 + lane,
                    &tiles[w][0][i * 64]);
    __builtin_amdgcn_sched_barrier(0);

    float4* oh4 = reinterpret_cast<float4*>(onehot);
    const float4 z4 = make_float4(0.f, 0.f, 0.f, 0.f);

#pragma unroll  // full: makes cqall[th] a static index (rule: no reg-arrays)
    for (int th = 0; th < 4; ++th) {
        const float cql = cqall[th];
        for (int sub = 0; sub < 2; ++sub) {
            const int t = th * 2 + sub;
            const int b = t & 1;

            // zero-store burst: 8 one_hot rows (this wave owns them)
            {
                const int zb = n0 + w * 64 + t * 8;
#pragma unroll
                for (int rr = 0; rr < 8; ++rr) {
                    float4* rp = oh4 + ((size_t)(zb + rr) * NCB + k) * 256;
#pragma unroll
                    for (int s = 0; s < 4; ++s) rp[s * 64 + lane] = z4;
                }
            }
            __builtin_amdgcn_sched_barrier(0);

            if (t < NTL - 1) {
                // stage next tile (async direct-to-LDS)
#pragma unroll
                for (int i = 0; i < 4; ++i)
                    gload_lds16(
                        cbk4 + ((size_t)qbase + (t + 1) * TILE) * 8 + i * 64 +
                            lane,
                        &tiles[w][b ^ 1][i * 64]);
                __builtin_amdgcn_sched_barrier(0);
                // FIFO: [gloads_t(4)][stores_t(32)][gloads_t+1(4)] ->
                // vmcnt(36) completes gloads_t, leaves stores in flight
                asm volatile("s_waitcnt vmcnt(36)" ::: "memory");
            } else {
                asm volatile("s_waitcnt vmcnt(32)" ::: "memory");
            }
            __builtin_amdgcn_sched_barrier(0);

            const f32x4* buf = &tiles[w][b][0];
#pragma unroll 2
            for (int c = 0; c < TILE; ++c) {
                const float cqv = __int_as_float(__builtin_amdgcn_readlane(
                    __float_as_int(cql), (sub << 5) + c));
                f32x4 A[8];
#pragma unroll
                for (int jj = 0; jj < 8; ++jj) A[jj] = buf[c * 8 + jj];
                const int cg = qbase + t * TILE + c;

#pragma unroll
                for (int j = 0; j < 4; ++j) {
                    // frozen chain: acc01=(d0,d1), acc23=(d2,d3), jj ascending
                    f32x2 acc01 = {0.f, 0.f}, acc23 = {0.f, 0.f};
#pragma unroll
                    for (int jj = 0; jj < 8; ++jj) {
                        const f32x2 alo =
                            __builtin_shufflevector(A[jj], A[jj], 0, 1);
                        const f32x2 ahi =
                            __builtin_shufflevector(A[jj], A[jj], 2, 3);
                        acc01 = pkfma(xlo[j][jj], alo, acc01);
                        acc23 = pkfma(xhi[j][jj], ahi, acc23);
                    }
                    const float dot =
                        (acc01.x + acc01.y) + (acc23.x + acc23.y);
                    const float dist = fmaf(-2.f, dot, xsq[j] + cqv);
                    if (dist < best[j]) {  // strict <: first occurrence
                        best[j] = dist;
                        bi[j] = cg;
                    }
                }
            }
        }
    }

    // ---- publish per-quarter partials ----
#pragma unroll
    for (int j = 0; j < 4; ++j) {
        pd[q][rbase + j] = best[j];
        pi[q][rbase + j] = bi[j];
    }
    __syncthreads();  // partials visible + ALL zero-stores drained (vmcnt 0)

    // ---- combine quarters + scatter; thread tid owns block-row tid ----
    {
        const int r = tid;
        float bd = pd[0][r];
        int bx = pi[0][r];
#pragma unroll
        for (int qq = 1; qq < 4; ++qq) {
            const float dq = pd[qq][r];
            const int iq = pi[qq][r];
            // ascending quarters => on tie keep lower (earlier) index
            if (dq < bd) {
                bd = dq;
                bx = iq;
            }
        }
        const int n = n0 + r;
        idxf[(size_t)n * NCB + k] = (float)bx;
        const f32x4* src = cbk4 + (size_t)bx * 8;
        f32x4* dst =
            reinterpret_cast<f32x4*>(xhat + ((size_t)n * NCB + k) * DIM);
#pragma unroll
        for (int jj = 0; jj < 8; ++jj) dst[jj] = src[jj];
        onehot[((size_t)n * NCB + k) * CB + bx] = 1.0f;
    }
}

extern "C" void kernel_launch(void* const* d_in, const int* in_sizes, int n_in,
                              void* d_out, int out_size, void* d_ws,
                              size_t ws_size, hipStream_t stream) {
    const float* x = (const float*)d_in[0];
    const float* cb = (const float*)d_in[1];
    const float* rb = (const float*)d_in[2];

    float* out = (float*)d_out;
    float* xhat = out;                             // N*NCB*DIM
    float* onehot = out + (size_t)NN * NCB * DIM;  // N*NCB*CB
    float* idxf = onehot + (size_t)NN * NCB * CB;  // N*NCB

    float* csqb = (float*)d_ws;  // NCB*CB floats = 32 KB

    vq_csq<<<(NCB * CB + 255) / 256, 256, 0, stream>>>(cb, rb, csqb);
    vq_fused<<<(NN / RPB) * NCB, 512, 0, stream>>>(x, cb, csqb, xhat, onehot,
                                                   idxf);
}